// Round 1
// baseline (168.270 us; speedup 1.0000x reference)
//
#include <hip/hip_runtime.h>

// Segmented gather: out[t] = req_to_token[req_pool_indices[r]*MAXLEN +
//                                         kv_start_idx[r] + (t - kv_indptr[r])]
// where r is the segment owning t (kv_indptr[r] <= t < kv_indptr[r+1]).
// B=64 segments, MAXLEN=16384. All int inputs arrive as int32; output int32.

#define NREQ 64
#define MAXLEN 16384

__global__ __launch_bounds__(256) void kv_gather_kernel(
    const int* __restrict__ req_to_token,
    const int* __restrict__ req_pool_indices,
    const int* __restrict__ kv_indptr,
    const int* __restrict__ kv_start_idx,
    int* __restrict__ out,
    int total)
{
    __shared__ int s_indptr[NREQ + 1];
    __shared__ int s_base[NREQ];   // pool_row*MAXLEN + start  (combined)

    const int tid = threadIdx.x;
    if (tid < NREQ + 1) s_indptr[tid] = kv_indptr[tid];
    if (tid < NREQ) {
        s_base[tid] = req_pool_indices[tid] * MAXLEN + kv_start_idx[tid];
    }
    __syncthreads();

    const int t0 = (blockIdx.x * 256 + tid) * 4;
    if (t0 >= total) return;

    // binary search: largest r with s_indptr[r] <= t0   (r in [0, NREQ-1])
    int lo = 0, hi = NREQ - 1;
    #pragma unroll
    for (int it = 0; it < 6; ++it) {          // ceil(log2(64)) = 6 steps
        int mid = (lo + hi + 1) >> 1;
        if (s_indptr[mid] <= t0) lo = mid; else hi = mid - 1;
    }
    int r = lo;

    if (t0 + 3 < total) {
        int4 v;
        int t = t0;
        // elem 0
        v.x = req_to_token[s_base[r] + (t - s_indptr[r])];
        // elems 1..3: segment index can only move forward
        ++t; while (t >= s_indptr[r + 1]) ++r;
        v.y = req_to_token[s_base[r] + (t - s_indptr[r])];
        ++t; while (t >= s_indptr[r + 1]) ++r;
        v.z = req_to_token[s_base[r] + (t - s_indptr[r])];
        ++t; while (t >= s_indptr[r + 1]) ++r;
        v.w = req_to_token[s_base[r] + (t - s_indptr[r])];
        *reinterpret_cast<int4*>(out + t0) = v;   // out + t0 is 16B-aligned
    } else {
        for (int t = t0; t < total; ++t) {
            while (t >= s_indptr[r + 1]) ++r;
            out[t] = req_to_token[s_base[r] + (t - s_indptr[r])];
        }
    }
}

extern "C" void kernel_launch(void* const* d_in, const int* in_sizes, int n_in,
                              void* d_out, int out_size, void* d_ws, size_t ws_size,
                              hipStream_t stream) {
    const int* req_to_token     = (const int*)d_in[0];
    const int* req_pool_indices = (const int*)d_in[1];
    // d_in[2] = page_kernel_lens (unused; lens are implicit in kv_indptr)
    const int* kv_indptr        = (const int*)d_in[3];
    const int* kv_start_idx     = (const int*)d_in[4];
    int* out = (int*)d_out;

    const int total   = out_size;
    const int threads = 256;
    const int blocks  = (total + threads * 4 - 1) / (threads * 4);
    kv_gather_kernel<<<blocks, threads, 0, stream>>>(
        req_to_token, req_pool_indices, kv_indptr, kv_start_idx, out, total);
}

// Round 2
// 166.361 us; speedup vs baseline: 1.0115x; 1.0115x over previous
//
#include <hip/hip_runtime.h>

// Segmented gather: out[t] = req_to_token[req_pool_indices[r]*MAXLEN +
//                                         kv_start_idx[r] + (t - kv_indptr[r])]
// where r is the segment owning t (kv_indptr[r] <= t < kv_indptr[r+1]).
// B=64 segments, MAXLEN=16384. All int inputs arrive as int32; output int32.
//
// Per-segment fused offset: gbase[r] = pool_row*MAXLEN + start - indptr[r],
// so the inner gather is simply req_to_token[gbase[r] + t].

#define NREQ 64
#define MAXLEN 16384

__global__ __launch_bounds__(256) void kv_gather_kernel(
    const int* __restrict__ req_to_token,
    const int* __restrict__ req_pool_indices,
    const int* __restrict__ kv_indptr,
    const int* __restrict__ kv_start_idx,
    int* __restrict__ out,
    int total)
{
    __shared__ int s_indptr[NREQ + 1];
    __shared__ int s_gbase[NREQ];   // pool_row*MAXLEN + start - indptr[r]

    const int tid = threadIdx.x;
    if (tid < NREQ + 1) s_indptr[tid] = kv_indptr[tid];
    __syncthreads();
    if (tid < NREQ) {
        s_gbase[tid] = req_pool_indices[tid] * MAXLEN + kv_start_idx[tid]
                       - s_indptr[tid];
    }
    __syncthreads();

    const int t0 = (blockIdx.x * 256 + tid) * 4;
    if (t0 >= total) return;

    // binary search: largest r with s_indptr[r] <= t0   (r in [0, NREQ-1])
    int lo = 0, hi = NREQ - 1;
    #pragma unroll
    for (int it = 0; it < 6; ++it) {          // ceil(log2(64)) = 6 steps
        int mid = (lo + hi + 1) >> 1;
        if (s_indptr[mid] <= t0) lo = mid; else hi = mid - 1;
    }
    int r = lo;

    if (t0 + 3 < total) {
        int4 v;
        int t = t0;
        v.x = req_to_token[s_gbase[r] + t];
        ++t; while (t >= s_indptr[r + 1]) ++r;
        v.y = req_to_token[s_gbase[r] + t];
        ++t; while (t >= s_indptr[r + 1]) ++r;
        v.z = req_to_token[s_gbase[r] + t];
        ++t; while (t >= s_indptr[r + 1]) ++r;
        v.w = req_to_token[s_gbase[r] + t];
        *reinterpret_cast<int4*>(out + t0) = v;   // out + t0 is 16B-aligned
    } else {
        for (int t = t0; t < total; ++t) {
            while (t >= s_indptr[r + 1]) ++r;
            out[t] = req_to_token[s_gbase[r] + t];
        }
    }
}

extern "C" void kernel_launch(void* const* d_in, const int* in_sizes, int n_in,
                              void* d_out, int out_size, void* d_ws, size_t ws_size,
                              hipStream_t stream) {
    const int* req_to_token     = (const int*)d_in[0];
    const int* req_pool_indices = (const int*)d_in[1];
    // d_in[2] = page_kernel_lens (unused; lens are implicit in kv_indptr)
    const int* kv_indptr        = (const int*)d_in[3];
    const int* kv_start_idx     = (const int*)d_in[4];
    int* out = (int*)d_out;

    const int total   = out_size;
    const int threads = 256;
    const int blocks  = (total + threads * 4 - 1) / (threads * 4);
    kv_gather_kernel<<<blocks, threads, 0, stream>>>(
        req_to_token, req_pool_indices, kv_indptr, kv_start_idx, out, total);
}